// Round 1
// 332.512 us; speedup vs baseline: 1.0044x; 1.0044x over previous
//
#include <hip/hip_runtime.h>

#define G_GROUPS 512
#define CNT      8192
#define S_PAIRS  8192
#define BLOCK    1024
#define WAVES    (BLOCK / 64)        // 16
#define PPT      (S_PAIRS / BLOCK)   // 8 pairs per thread

// Raw record stream: 9 dwords (36 B) per record, CA row = dwords [9r+3, 9r+6).
#define RAW_DW    (CNT * 9)          // 73728 dwords per group per tensor
#define TILE_REC  512                // records per pipeline tile
#define TILE_DW   (TILE_REC * 9)     // 4608 dwords = 18 KiB raw
#define TAB_TILE  (TILE_REC * 3)     // 1536 dwords packed float3
#define NTILES    (CNT / TILE_REC)   // 16
#define NBUF      3                  // raw double+1 buffers (hazard-free at 2-ahead)
#define CHUNK_DW  256                // one global_load_lds(16B x 64 lanes) = 1 KiB
#define NCHUNK    (TILE_DW / CHUNK_DW) // 18 DMA instrs per tile
#define ISSUERS   9                  // waves 0..8 issue 2 chunks each

typedef __attribute__((address_space(3))) void  lds_void;
typedef const __attribute__((address_space(1))) void g_void;

// Raw barrier WITHOUT vmcnt drain (counted-vmcnt pipeline, T3/T4 pattern).
// lgkmcnt(0) publishes this wave's ds ops; empty asm = compiler memory fence
// so DMA issues / LDS ops cannot be hoisted across the barrier.
__device__ __forceinline__ void fencebar() {
    asm volatile("s_waitcnt lgkmcnt(0)" ::: "memory");
    __builtin_amdgcn_s_barrier();
    asm volatile("" ::: "memory");
}

// Issue one tile's worth of this wave's DMA chunks: dense, lane-contiguous,
// perfectly coalesced 16 B/lane. LDS dest is wave-uniform base (+lane*16 in HW).
__device__ __forceinline__ void issue_tile(const float* __restrict__ src, int t,
                                           float* rb, int wid, int lane) {
    const int c0 = 2 * wid;                       // chunks 2w, 2w+1  (w < 9)
    const float* gp0 = src + (size_t)t * TILE_DW + c0 * CHUNK_DW + lane * 4;
    __builtin_amdgcn_global_load_lds((g_void*)gp0,
                                     (lds_void*)(rb + c0 * CHUNK_DW), 16, 0, 0);
    const float* gp1 = gp0 + CHUNK_DW;
    __builtin_amdgcn_global_load_lds((g_void*)gp1,
                                     (lds_void*)(rb + c0 * CHUNK_DW + CHUNK_DW), 16, 0, 0);
}

// Pipelined stage of one tensor into tab[]. Prologue (tiles 0,1) must already
// be issued. Steady state: 2 tiles (4 DMA instrs/wave) in flight; vmcnt(2)
// retires exactly tile t. Single barrier per tile. Extraction is dword-linear:
// thread tid copies tab-dword (t*1536 + tid) [+1024 strip], conflict-free.
#define STAGE_PIPE(SRC)                                                          \
    _Pragma("unroll")                                                            \
    for (int t = 0; t < NTILES; ++t) {                                           \
        if (wid < ISSUERS) {                                                     \
            if (t < NTILES - 1) asm volatile("s_waitcnt vmcnt(2)" ::: "memory"); \
            else                asm volatile("s_waitcnt vmcnt(0)" ::: "memory"); \
        }                                                                        \
        fencebar();                                                              \
        {                                                                        \
            const float* rb = &raw[t % NBUF][0];                                 \
            float*       tb = &tab[t * TAB_TILE];                                \
            tb[d0] = rb[rI0];                                                    \
            if (do2) tb[d1] = rb[rI1];                                           \
        }                                                                        \
        if (wid < ISSUERS && t + 2 < NTILES)                                     \
            issue_tile(SRC, t + 2, &raw[(t + 2) % NBUF][0], wid, lane);          \
    }                                                                            \
    fencebar();

__global__ __launch_bounds__(BLOCK) void rgn_loss_kernel(
    const float* __restrict__ inputs,
    const float* __restrict__ target,
    const int*   __restrict__ left,
    const int*   __restrict__ right,
    float*       __restrict__ out)
{
    // Packed float3 CA table (96 KiB) + 3 raw tile buffers (54 KiB) = 150 KiB.
    __shared__ float tab[3 * CNT];
    __shared__ float raw[NBUF][TILE_DW];
    __shared__ float red[WAVES];

    const int tid   = threadIdx.x;
    const int lane  = tid & 63;
    const int wid   = tid >> 6;
    const int g     = blockIdx.x;
    const int gbase = g * CNT;

    const float* srcA = inputs + (size_t)g * RAW_DW;
    const float* srcB = target + (size_t)g * RAW_DW;

    // ---- Pair indices (coalesced; retire under the first counted vmcnt) ----
    const size_t pbase = (size_t)g * S_PAIRS;
    int li[PPT], ri[PPT];
    #pragma unroll
    for (int i = 0; i < PPT; ++i) {
        li[i] = left [pbase + tid + i * BLOCK] - gbase;   // group-local by construction
        ri[i] = right[pbase + tid + i * BLOCK] - gbase;
    }

    // ---- Per-thread extraction constants: tab dword d -> raw dword 9*(d/3)+3+d%3
    const int d0  = tid;
    const int j0  = d0 / 3;
    const int rI0 = 9 * j0 + 3 + (d0 - 3 * j0);
    const int d1  = tid + BLOCK;
    const int j1  = d1 / 3;
    const int rI1 = 9 * j1 + 3 + (d1 - 3 * j1);
    const bool do2 = (tid < TAB_TILE - BLOCK);            // tid < 512

    // ---- Inputs: prologue + pipelined stage ----
    if (wid < ISSUERS) {
        issue_tile(srcA, 0, &raw[0][0], wid, lane);
        issue_tile(srcA, 1, &raw[1][0], wid, lane);
    }
    STAGE_PIPE(srcA)

    // ---- Target prologue NOW: 2 tiles stream in under the d_in gather ----
    if (wid < ISSUERS) {
        issue_tile(srcB, 0, &raw[0][0], wid, lane);
        issue_tile(srcB, 1, &raw[1][0], wid, lane);
    }

    // ---- Gather d_in from packed table ----
    float din[PPT];
    #pragma unroll
    for (int i = 0; i < PPT; ++i) {
        const int a = 3 * li[i], b = 3 * ri[i];
        const float dx = tab[a]     - tab[b];
        const float dy = tab[a + 1] - tab[b + 1];
        const float dz = tab[a + 2] - tab[b + 2];
        din[i] = sqrtf(dx * dx + dy * dy + dz * dz);
    }

    // ---- Target: pipelined stage (iter-0 barrier orders gather reads before
    //      the table overwrite; raw buffers were free of input-tile readers) ----
    STAGE_PIPE(srcB)

    // ---- Gather d_tg, accumulate squared difference ----
    float acc = 0.0f;
    #pragma unroll
    for (int i = 0; i < PPT; ++i) {
        const int a = 3 * li[i], b = 3 * ri[i];
        const float dx = tab[a]     - tab[b];
        const float dy = tab[a + 1] - tab[b + 1];
        const float dz = tab[a + 2] - tab[b + 2];
        const float d  = din[i] - sqrtf(dx * dx + dy * dy + dz * dz);
        acc += d * d;
    }

    // ---- Block reduction -> one atomic ----
    #pragma unroll
    for (int off = 32; off > 0; off >>= 1)
        acc += __shfl_down(acc, off);
    if (lane == 0) red[wid] = acc;
    __syncthreads();
    if (wid == 0) {
        float v = (lane < WAVES) ? red[lane] : 0.0f;
        #pragma unroll
        for (int off = 8; off > 0; off >>= 1)
            v += __shfl_down(v, off);
        if (lane == 0)
            atomicAdd(out, v * (1.0f / ((float)G_GROUPS * (float)S_PAIRS)));
    }
}

extern "C" void kernel_launch(void* const* d_in, const int* in_sizes, int n_in,
                              void* d_out, int out_size, void* d_ws, size_t ws_size,
                              hipStream_t stream) {
    const float* inputs = (const float*)d_in[0];
    const float* target = (const float*)d_in[1];
    const int*   left   = (const int*)d_in[2];
    const int*   right  = (const int*)d_in[3];
    float*       out    = (float*)d_out;

    hipMemsetAsync(out, 0, sizeof(float), stream);   // graph-capture safe
    rgn_loss_kernel<<<G_GROUPS, BLOCK, 0, stream>>>(inputs, target, left, right, out);
}